// Round 3
// baseline (108.284 us; speedup 1.0000x reference)
//
#include <hip/hip_runtime.h>

// Problem constants (B,S,H) = (8,2048,4096), N_POOL=6, N_LAYERS=32
constexpr int kS     = 2048;
constexpr int kH     = 4096;
constexpr int kNPOOL = 6;
constexpr int kNLAY  = 32;
constexpr int kNK    = 7;    // N_POOL + 1
constexpr int kRPB   = 8;    // rows per block

// Native vector type: __builtin_nontemporal_* requires a scalar/native-vector
// pointee (HIP's float4 class is rejected).
typedef float f32x4 __attribute__((ext_vector_type(4)));

// 2048 blocks x 256 threads; block bi owns rows [bi*8, bi*8+8).
// Gate rows (s == S-1) are 2048 apart -> at most one per block.
__global__ __launch_bounds__(256) void fused_gate_copy(
    const float* __restrict__ x,
    const float* __restrict__ gate_w,
    const float* __restrict__ gate_b,
    const float* __restrict__ pool,
    const int*   __restrict__ layer_idx_p,
    float*       __restrict__ out)
{
    const int tid  = threadIdx.x;
    const int row0 = blockIdx.x * kRPB;

    __shared__ float red[4][kNK];

    for (int r = 0; r < kRPB; ++r) {
        const int row = row0 + r;
        const int s   = row & (kS - 1);
        const size_t base = (size_t)row * kH;

        if (s != kS - 1) {
            // streaming copy: 4 NT loads, then 4 NT stores (max MLP, no cache alloc)
            const f32x4* __restrict__ srcv = reinterpret_cast<const f32x4*>(x + base);
            f32x4*       __restrict__ dstv = reinterpret_cast<f32x4*>(out + base);
            f32x4 v0 = __builtin_nontemporal_load(srcv + (tid + 0 * 256));
            f32x4 v1 = __builtin_nontemporal_load(srcv + (tid + 1 * 256));
            f32x4 v2 = __builtin_nontemporal_load(srcv + (tid + 2 * 256));
            f32x4 v3 = __builtin_nontemporal_load(srcv + (tid + 3 * 256));
            __builtin_nontemporal_store(v0, dstv + (tid + 0 * 256));
            __builtin_nontemporal_store(v1, dstv + (tid + 1 * 256));
            __builtin_nontemporal_store(v2, dstv + (tid + 2 * 256));
            __builtin_nontemporal_store(v3, dstv + (tid + 3 * 256));
            continue;
        }

        // ---- gate path (8 rows total across the grid) ----
        const float4* __restrict__ src = reinterpret_cast<const float4*>(x + base);
        float4*       __restrict__ dst = reinterpret_cast<float4*>(out + base);

        const int b = row >> 11;              // row / S
        const int L = *layer_idx_p;

        // tok = x[b, S-1, :]
        float4 tokv[4];
        #pragma unroll
        for (int i = 0; i < 4; ++i) tokv[i] = src[tid + i * 256];

        // score[k] = sum_h tok[h] * gate_w[k][h]
        float acc[kNK];
        #pragma unroll
        for (int k = 0; k < kNK; ++k) acc[k] = 0.0f;

        #pragma unroll
        for (int k = 0; k < kNK; ++k) {
            const float4* wv = reinterpret_cast<const float4*>(gate_w + (size_t)k * kH);
            #pragma unroll
            for (int i = 0; i < 4; ++i) {
                const float4 w = wv[tid + i * 256];
                const float4 t = tokv[i];
                acc[k] += t.x * w.x + t.y * w.y + t.z * w.z + t.w * w.w;
            }
        }

        // 64-lane wave reduction
        #pragma unroll
        for (int k = 0; k < kNK; ++k) {
            float v = acc[k];
            #pragma unroll
            for (int off = 32; off > 0; off >>= 1)
                v += __shfl_down(v, off, 64);
            acc[k] = v;
        }

        // cross-wave reduction via LDS (4 waves)
        const int lane = tid & 63;
        const int wave = tid >> 6;
        if (lane == 0) {
            #pragma unroll
            for (int k = 0; k < kNK; ++k) red[wave][k] = acc[k];
        }
        __syncthreads();

        float score[kNK];
        #pragma unroll
        for (int k = 0; k < kNK; ++k)
            score[k] = red[0][k] + red[1][k] + red[2][k] + red[3][k] + gate_b[k];

        // softmax over 7 (redundant per thread)
        float m = score[0];
        #pragma unroll
        for (int k = 1; k < kNK; ++k) m = fmaxf(m, score[k]);
        float p[kNK];
        float sum = 0.0f;
        #pragma unroll
        for (int k = 0; k < kNK; ++k) { p[k] = expf(score[k] - m); sum += p[k]; }
        const float inv = 1.0f / sum;
        #pragma unroll
        for (int k = 0; k < kNK; ++k) p[k] *= inv;

        // new_vec = sum_{k<6} p[k]*pool[b,k,L,:] + p[6]*tok
        const size_t poolb = ((size_t)b * kNPOOL) * (size_t)(kNLAY * kH) + (size_t)L * kH;
        #pragma unroll
        for (int i = 0; i < 4; ++i) {
            const int v = tid + i * 256;
            const float4 t = tokv[i];
            float4 o;
            o.x = p[kNK - 1] * t.x;
            o.y = p[kNK - 1] * t.y;
            o.z = p[kNK - 1] * t.z;
            o.w = p[kNK - 1] * t.w;
            #pragma unroll
            for (int k = 0; k < kNPOOL; ++k) {
                const float4* pv = reinterpret_cast<const float4*>(
                    pool + poolb + (size_t)k * (size_t)(kNLAY * kH));
                const float4 q = pv[v];
                o.x += p[k] * q.x;
                o.y += p[k] * q.y;
                o.z += p[k] * q.z;
                o.w += p[k] * q.w;
            }
            dst[v] = o;
        }
    }
}

extern "C" void kernel_launch(void* const* d_in, const int* in_sizes, int n_in,
                              void* d_out, int out_size, void* d_ws, size_t ws_size,
                              hipStream_t stream) {
    const float* x      = (const float*)d_in[0];   // (8, 2048, 4096) f32
    const float* gate_w = (const float*)d_in[1];   // (7, 4096) f32
    const float* gate_b = (const float*)d_in[2];   // (7,) f32
    const float* pool   = (const float*)d_in[3];   // (8, 6, 32, 4096) f32
    const int*   lidx   = (const int*)d_in[4];     // scalar int
    float*       out    = (float*)d_out;           // (8, 2048, 4096) f32

    const int rows   = out_size / kH;              // B*S = 16384
    const int blocks = rows / kRPB;                // 2048
    fused_gate_copy<<<blocks, 256, 0, stream>>>(x, gate_w, gate_b, pool, lidx, out);
}

// Round 4
// 106.982 us; speedup vs baseline: 1.0122x; 1.0122x over previous
//
#include <hip/hip_runtime.h>

// Problem constants (B,S,H) = (8,2048,4096), N_POOL=6, N_LAYERS=32
constexpr int kS     = 2048;
constexpr int kH     = 4096;
constexpr int kNPOOL = 6;
constexpr int kNLAY  = 32;
constexpr int kNK    = 7;    // N_POOL + 1

typedef float f32x4 __attribute__((ext_vector_type(4)));

// ---------------- Kernel A: pure flat copy (the 6.29 TB/s pattern) ---------
// Branchless grid-stride float4 copy of the whole x -> out (256 MiB).
// 2048 blocks x 256 threads x 4 float4/iter -> 8 full sweeps, exact fit.
__global__ __launch_bounds__(256) void flat_copy(
    const f32x4* __restrict__ src,
    f32x4*       __restrict__ dst,
    const int n4)
{
    const int stride = gridDim.x * blockDim.x * 4;
    int i = blockIdx.x * (blockDim.x * 4) + threadIdx.x;
    for (; i + 768 < n4; i += stride) {
        const f32x4 v0 = src[i + 0 * 256];
        const f32x4 v1 = src[i + 1 * 256];
        const f32x4 v2 = src[i + 2 * 256];
        const f32x4 v3 = src[i + 3 * 256];
        dst[i + 0 * 256] = v0;
        dst[i + 1 * 256] = v1;
        dst[i + 2 * 256] = v2;
        dst[i + 3 * 256] = v3;
    }
}

// ---------------- Kernel B: gate on the 8 last-token rows -------------------
// One block per batch (8 blocks x 256 threads). Overwrites out[b, S-1, :].
__global__ __launch_bounds__(256) void gate_rows(
    const float* __restrict__ x,
    const float* __restrict__ gate_w,
    const float* __restrict__ gate_b,
    const float* __restrict__ pool,
    const int*   __restrict__ layer_idx_p,
    float*       __restrict__ out)
{
    const int b   = blockIdx.x;
    const int tid = threadIdx.x;
    const int L   = *layer_idx_p;

    const size_t base = ((size_t)b * kS + (kS - 1)) * kH;
    const float4* __restrict__ src = reinterpret_cast<const float4*>(x + base);
    float4*       __restrict__ dst = reinterpret_cast<float4*>(out + base);

    // tok = x[b, S-1, :]
    float4 tokv[4];
    #pragma unroll
    for (int i = 0; i < 4; ++i) tokv[i] = src[tid + i * 256];

    // score[k] = sum_h tok[h] * gate_w[k][h]
    float acc[kNK];
    #pragma unroll
    for (int k = 0; k < kNK; ++k) acc[k] = 0.0f;

    #pragma unroll
    for (int k = 0; k < kNK; ++k) {
        const float4* wv = reinterpret_cast<const float4*>(gate_w + (size_t)k * kH);
        #pragma unroll
        for (int i = 0; i < 4; ++i) {
            const float4 w = wv[tid + i * 256];
            const float4 t = tokv[i];
            acc[k] += t.x * w.x + t.y * w.y + t.z * w.z + t.w * w.w;
        }
    }

    // 64-lane wave reduction
    #pragma unroll
    for (int k = 0; k < kNK; ++k) {
        float v = acc[k];
        #pragma unroll
        for (int off = 32; off > 0; off >>= 1)
            v += __shfl_down(v, off, 64);
        acc[k] = v;
    }

    // cross-wave reduction via LDS (4 waves)
    __shared__ float red[4][kNK];
    const int lane = tid & 63;
    const int wave = tid >> 6;
    if (lane == 0) {
        #pragma unroll
        for (int k = 0; k < kNK; ++k) red[wave][k] = acc[k];
    }
    __syncthreads();

    float score[kNK];
    #pragma unroll
    for (int k = 0; k < kNK; ++k)
        score[k] = red[0][k] + red[1][k] + red[2][k] + red[3][k] + gate_b[k];

    // softmax over 7 (redundant per thread)
    float m = score[0];
    #pragma unroll
    for (int k = 1; k < kNK; ++k) m = fmaxf(m, score[k]);
    float p[kNK];
    float sum = 0.0f;
    #pragma unroll
    for (int k = 0; k < kNK; ++k) { p[k] = expf(score[k] - m); sum += p[k]; }
    const float inv = 1.0f / sum;
    #pragma unroll
    for (int k = 0; k < kNK; ++k) p[k] *= inv;

    // new_vec = sum_{k<6} p[k]*pool[b,k,L,:] + p[6]*tok
    const size_t poolb = ((size_t)b * kNPOOL) * (size_t)(kNLAY * kH) + (size_t)L * kH;
    #pragma unroll
    for (int i = 0; i < 4; ++i) {
        const int v = tid + i * 256;
        const float4 t = tokv[i];
        float4 o;
        o.x = p[kNK - 1] * t.x;
        o.y = p[kNK - 1] * t.y;
        o.z = p[kNK - 1] * t.z;
        o.w = p[kNK - 1] * t.w;
        #pragma unroll
        for (int k = 0; k < kNPOOL; ++k) {
            const float4* pv = reinterpret_cast<const float4*>(
                pool + poolb + (size_t)k * (size_t)(kNLAY * kH));
            const float4 q = pv[v];
            o.x += p[k] * q.x;
            o.y += p[k] * q.y;
            o.z += p[k] * q.z;
            o.w += p[k] * q.w;
        }
        dst[v] = o;
    }
}

extern "C" void kernel_launch(void* const* d_in, const int* in_sizes, int n_in,
                              void* d_out, int out_size, void* d_ws, size_t ws_size,
                              hipStream_t stream) {
    const float* x      = (const float*)d_in[0];   // (8, 2048, 4096) f32
    const float* gate_w = (const float*)d_in[1];   // (7, 4096) f32
    const float* gate_b = (const float*)d_in[2];   // (7,) f32
    const float* pool   = (const float*)d_in[3];   // (8, 6, 32, 4096) f32
    const int*   lidx   = (const int*)d_in[4];     // scalar int
    float*       out    = (float*)d_out;           // (8, 2048, 4096) f32

    const int n4 = out_size / 4;                   // 16,777,216 float4
    flat_copy<<<2048, 256, 0, stream>>>(
        reinterpret_cast<const f32x4*>(x), reinterpret_cast<f32x4*>(out), n4);

    gate_rows<<<8, 256, 0, stream>>>(x, gate_w, gate_b, pool, lidx, out);
}

// Round 5
// 82.904 us; speedup vs baseline: 1.3061x; 1.2904x over previous
//
#include <hip/hip_runtime.h>

// Problem constants (B,S,H) = (8,2048,4096), N_POOL=6, N_LAYERS=32
constexpr int kS     = 2048;
constexpr int kH     = 4096;
constexpr int kNPOOL = 6;
constexpr int kNLAY  = 32;
constexpr int kNK    = 7;    // N_POOL + 1

// Native vector type: __builtin_nontemporal_* rejects HIP's float4 class.
typedef float f32x4 __attribute__((ext_vector_type(4)));

// R1 structure (best measured): one block per (b,s) row, 16384 blocks x 256
// threads. Copy path: CACHED loads (let L3 keep x resident across replays),
// NONTEMPORAL stores (don't let out's store-allocations evict x from L3).
__global__ __launch_bounds__(256) void fused_gate_copy(
    const float* __restrict__ x,
    const float* __restrict__ gate_w,
    const float* __restrict__ gate_b,
    const float* __restrict__ pool,
    const int*   __restrict__ layer_idx_p,
    float*       __restrict__ out)
{
    const int row  = blockIdx.x;          // row = b*S + s
    const int s    = row & (kS - 1);
    const int tid  = threadIdx.x;
    const size_t base = (size_t)row * kH;

    if (s != kS - 1) {
        // cached loads + NT stores
        const f32x4* __restrict__ srcv = reinterpret_cast<const f32x4*>(x + base);
        f32x4*       __restrict__ dstv = reinterpret_cast<f32x4*>(out + base);
        const f32x4 v0 = srcv[tid + 0 * 256];
        const f32x4 v1 = srcv[tid + 1 * 256];
        const f32x4 v2 = srcv[tid + 2 * 256];
        const f32x4 v3 = srcv[tid + 3 * 256];
        __builtin_nontemporal_store(v0, dstv + (tid + 0 * 256));
        __builtin_nontemporal_store(v1, dstv + (tid + 1 * 256));
        __builtin_nontemporal_store(v2, dstv + (tid + 2 * 256));
        __builtin_nontemporal_store(v3, dstv + (tid + 3 * 256));
        return;
    }

    // ---- gate path (8 blocks of 16384) ----
    const float4* __restrict__ src = reinterpret_cast<const float4*>(x + base);
    float4*       __restrict__ dst = reinterpret_cast<float4*>(out + base);

    const int b = row >> 11;              // row / S
    const int L = *layer_idx_p;

    // tok = x[b, S-1, :]
    float4 tokv[4];
    #pragma unroll
    for (int i = 0; i < 4; ++i) tokv[i] = src[tid + i * 256];

    // score[k] = sum_h tok[h] * gate_w[k][h]
    float acc[kNK];
    #pragma unroll
    for (int k = 0; k < kNK; ++k) acc[k] = 0.0f;

    #pragma unroll
    for (int k = 0; k < kNK; ++k) {
        const float4* wv = reinterpret_cast<const float4*>(gate_w + (size_t)k * kH);
        #pragma unroll
        for (int i = 0; i < 4; ++i) {
            const float4 w = wv[tid + i * 256];
            const float4 t = tokv[i];
            acc[k] += t.x * w.x + t.y * w.y + t.z * w.z + t.w * w.w;
        }
    }

    // 64-lane wave reduction
    #pragma unroll
    for (int k = 0; k < kNK; ++k) {
        float v = acc[k];
        #pragma unroll
        for (int off = 32; off > 0; off >>= 1)
            v += __shfl_down(v, off, 64);
        acc[k] = v;
    }

    // cross-wave reduction via LDS (4 waves)
    __shared__ float red[4][kNK];
    const int lane = tid & 63;
    const int wave = tid >> 6;
    if (lane == 0) {
        #pragma unroll
        for (int k = 0; k < kNK; ++k) red[wave][k] = acc[k];
    }
    __syncthreads();

    float score[kNK];
    #pragma unroll
    for (int k = 0; k < kNK; ++k)
        score[k] = red[0][k] + red[1][k] + red[2][k] + red[3][k] + gate_b[k];

    // softmax over 7 (redundant per thread)
    float m = score[0];
    #pragma unroll
    for (int k = 1; k < kNK; ++k) m = fmaxf(m, score[k]);
    float p[kNK];
    float sum = 0.0f;
    #pragma unroll
    for (int k = 0; k < kNK; ++k) { p[k] = expf(score[k] - m); sum += p[k]; }
    const float inv = 1.0f / sum;
    #pragma unroll
    for (int k = 0; k < kNK; ++k) p[k] *= inv;

    // new_vec = sum_{k<6} p[k]*pool[b,k,L,:] + p[6]*tok
    const size_t poolb = ((size_t)b * kNPOOL) * (size_t)(kNLAY * kH) + (size_t)L * kH;
    #pragma unroll
    for (int i = 0; i < 4; ++i) {
        const int v = tid + i * 256;
        const float4 t = tokv[i];
        float4 o;
        o.x = p[kNK - 1] * t.x;
        o.y = p[kNK - 1] * t.y;
        o.z = p[kNK - 1] * t.z;
        o.w = p[kNK - 1] * t.w;
        #pragma unroll
        for (int k = 0; k < kNPOOL; ++k) {
            const float4* pv = reinterpret_cast<const float4*>(
                pool + poolb + (size_t)k * (size_t)(kNLAY * kH));
            const float4 q = pv[v];
            o.x += p[k] * q.x;
            o.y += p[k] * q.y;
            o.z += p[k] * q.z;
            o.w += p[k] * q.w;
        }
        dst[v] = o;
    }
}

extern "C" void kernel_launch(void* const* d_in, const int* in_sizes, int n_in,
                              void* d_out, int out_size, void* d_ws, size_t ws_size,
                              hipStream_t stream) {
    const float* x      = (const float*)d_in[0];   // (8, 2048, 4096) f32
    const float* gate_w = (const float*)d_in[1];   // (7, 4096) f32
    const float* gate_b = (const float*)d_in[2];   // (7,) f32
    const float* pool   = (const float*)d_in[3];   // (8, 6, 32, 4096) f32
    const int*   lidx   = (const int*)d_in[4];     // scalar int
    float*       out    = (float*)d_out;           // (8, 2048, 4096) f32

    const int rows = out_size / kH;                // B*S = 16384
    fused_gate_copy<<<rows, 256, 0, stream>>>(x, gate_w, gate_b, pool, lidx, out);
}